// Round 21
// baseline (106.087 us; speedup 1.0000x reference)
//
#include <hip/hip_runtime.h>

// Separable 3D Gaussian blur (sigma=1, truncate=3 -> 7 taps), SAME zero padding.
// (N=2, D=160, H=160, W=160, C=4) float32 == float4 over C.
// Round 21 = R18/R19 (zero-barrier wave-autonomous 16x16 tiles, best 70.4us)
// + staging moved to the VMEM pipe via __builtin_amdgcn_global_load_lds:
//  - raw = flat [2][22 rows x stride 23] f4, double-buffered. gload_lds writes
//    wave-uniform base + lane*16 -> 8 rounds of 64 slots. Col 22 of each row
//    is a junk pad (fetched from slice base, never read): stride 23 makes
//    W-read bank-quads (7r+c)&7 perfectly balanced -> conflict-free (R17's
//    flat-22 layout was a 4-quad pileup; that, plus barriers, sank it).
//  - no prefetch registers (-32 VGPR), no ds_write commit phase: DS-ops/slice
//    46 -> 38 on the busiest pipe; stage bytes ride the ~40%-busy VMEM pipe.
//  - counted waits (R17-verified): vmcnt(0) while no stores outstanding
//    (k<=6), vmcnt(4) after -- the 4 stores are always the newest vmem ops,
//    so the count is independent of how many gloads were exec-masked off.
//  - boundary: real-but-outside-image slots pre-zeroed once (gloads are
//    exec-masked per lane -> never overwritten); D-OOB slices zero-fill via
//    ds_write (6 of 22 slices at chunk edges only).
// Kept: CHUNK=16, 2000 1-wave blocks (= 8 XCDs x 250 exact swizzle), W-blur
// 88 groups x (10 reads -> 4 wb outputs), H-blur 4 rows/lane + 4 D-rings.

#define THT 16
#define TWT 16
#define CHUNK 16
#define NS (CHUNK + 6)      // 22 slices per wave
#define DIM 160
#define SLICE (DIM * DIM)
#define RSTR 23             // raw row stride in f4 (22 real + 1 junk pad)
#define RTOT (22 * RSTR)    // 506 slots; 8 gload rounds cover 512
#define NBLK 2000           // 2n x 10th x 10tw x 10chunk = 8 XCDs x 250

#define W0 0.004433048f
#define W1 0.054005582f
#define W2 0.242036229f
#define W3 0.399050300f

__device__ __forceinline__ float4 blur7(float4 a0, float4 a1, float4 a2, float4 a3,
                                        float4 a4, float4 a5, float4 a6) {
    float4 r;
    r.x = W0 * (a0.x + a6.x) + W1 * (a1.x + a5.x) + W2 * (a2.x + a4.x) + W3 * a3.x;
    r.y = W0 * (a0.y + a6.y) + W1 * (a1.y + a5.y) + W2 * (a2.y + a4.y) + W3 * a3.y;
    r.z = W0 * (a0.z + a6.z) + W1 * (a1.z + a5.z) + W2 * (a2.z + a4.z) + W3 * a3.z;
    r.w = W0 * (a0.w + a6.w) + W1 * (a1.w + a5.w) + W2 * (a2.w + a4.w) + W3 * a3.w;
    return r;
}

typedef __attribute__((address_space(3))) void lds_void_t;
typedef const __attribute__((address_space(1))) void gbl_void_t;

// HBM -> LDS direct: 16B/lane at (wave-uniform base) + lane*16.
__device__ __forceinline__ void gload16(const float4* g, float4* l) {
    __builtin_amdgcn_global_load_lds((gbl_void_t*)g, (lds_void_t*)l, 16, 0, 0);
}

__global__ __launch_bounds__(64, 2)
void gauss3d_fused(const float4* __restrict__ in, float4* __restrict__ out) {
    // bijective XCD-chunked swizzle: 2000 = 8 * 250 exactly.
    const int bid = blockIdx.x;
    int wid = (bid & 7) * (NBLK / 8) + (bid >> 3);

    const int lane = threadIdx.x;   // 0..63

    const int tw    = wid % 10;  wid /= 10;
    const int th    = wid % 10;  wid /= 10;
    const int chunk = wid % 10;  wid /= 10;
    const int n     = wid;          // 0..1

    const int h0 = th * THT;
    const int w0 = tw * TWT;
    const int d0 = chunk * CHUNK;

    __shared__ float4 raw[2][512];   // flat 22 x (22+1 junk) f4, dbuf
    __shared__ float4 wb[22][17];    // W-blurred tile, +1 col pad

    const size_t nbase = (size_t)n * DIM * SLICE;
    const float4 z = make_float4(0.f, 0.f, 0.f, 0.f);

    // ---- stage constants: 8 rounds of 64 slots; slot j -> (j/23, j%23) ----
    int  soff[8];
    bool sok[8], rreal[8];
    #pragma unroll
    for (int s = 0; s < 8; ++s) {
        const int j = lane + 64 * s;
        const int rr = j / RSTR, cc = j % RSTR;
        const bool real = (j < RTOT) && (cc < 22);
        const int gh = h0 + rr - 3, gw = w0 + cc - 3;
        const bool ok = real && gh >= 0 && gh < DIM && gw >= 0 && gw < DIM;
        soff[s]  = ok ? (gh * DIM + gw) : 0;   // junk/masked lanes: slice base
        sok[s]   = ok;
        rreal[s] = real;
    }

    // pre-zero real-but-outside-image slots in BOTH buffers (gloads are
    // exec-masked to sok, so these are never overwritten afterwards)
    #pragma unroll
    for (int s = 0; s < 8; ++s) {
        if (rreal[s] && !sok[s]) {
            raw[0][lane + 64 * s] = z;
            raw[1][lane + 64 * s] = z;
        }
    }

    // ---- W-blur groups: 88 groups of 4 outputs ----
    const int g1r = lane >> 2, g1c = (lane & 3) * 4;
    const bool hasG2 = (lane < 24);
    const int g2r = (64 + lane) >> 2, g2c = ((64 + lane) & 3) * 4;
    const int w1base = g1r * RSTR + g1c;
    const int w2base = g2r * RSTR + g2c;

    // ---- H-blur: q = lane>>4 -> rows 4q..4q+3, lw = lane&15 ----
    const int q  = lane >> 4;
    const int lw = lane & 15;

    // 4 D-rings (output rows 4q..4q+3), 7 deep each
    float4 qa0=z,qa1=z,qa2=z,qa3=z,qa4=z,qa5=z,qa6=z;
    float4 qb0=z,qb1=z,qb2=z,qb3=z,qb4=z,qb5=z,qb6=z;
    float4 qc0=z,qc1=z,qc2=z,qc3=z,qc4=z,qc5=z,qc6=z;
    float4 qd0=z,qd1=z,qd2=z,qd3=z,qd4=z,qd5=z,qd6=z;

#define STAGE(BUF, DSL)                                                      \
    do {                                                                     \
        const int _d = (DSL);                                                \
        if (_d >= 0 && _d < DIM) {                                           \
            const float4* _g = in + nbase + (size_t)_d * SLICE;              \
            float4* _l = &raw[BUF][0];                                       \
            if (sok[0]) gload16(_g + soff[0], _l + 0);                       \
            if (sok[1]) gload16(_g + soff[1], _l + 64);                      \
            if (sok[2]) gload16(_g + soff[2], _l + 128);                     \
            if (sok[3]) gload16(_g + soff[3], _l + 192);                     \
            if (sok[4]) gload16(_g + soff[4], _l + 256);                     \
            if (sok[5]) gload16(_g + soff[5], _l + 320);                     \
            if (sok[6]) gload16(_g + soff[6], _l + 384);                     \
            if (sok[7]) gload16(_g + soff[7], _l + 448);                     \
        } else {                                                             \
            if (rreal[0]) raw[BUF][lane + 0]   = z;                          \
            if (rreal[1]) raw[BUF][lane + 64]  = z;                          \
            if (rreal[2]) raw[BUF][lane + 128] = z;                          \
            if (rreal[3]) raw[BUF][lane + 192] = z;                          \
            if (rreal[4]) raw[BUF][lane + 256] = z;                          \
            if (rreal[5]) raw[BUF][lane + 320] = z;                          \
            if (rreal[6]) raw[BUF][lane + 384] = z;                          \
            if (rreal[7]) raw[BUF][lane + 448] = z;                          \
        }                                                                    \
    } while (0)

#define WGRP(BASE, R, C0)                                                    \
    do {                                                                     \
        const float4* _rr = &raw[buf][BASE];                                 \
        float4 v0 = _rr[0];                                                  \
        float4 v1 = _rr[1];                                                  \
        float4 v2 = _rr[2];                                                  \
        float4 v3 = _rr[3];                                                  \
        float4 v4 = _rr[4];                                                  \
        float4 v5 = _rr[5];                                                  \
        float4 v6 = _rr[6];                                                  \
        float4 v7 = _rr[7];                                                  \
        float4 v8 = _rr[8];                                                  \
        float4 v9 = _rr[9];                                                  \
        float4* _wr = &wb[R][0];                                             \
        _wr[(C0) + 0] = blur7(v0, v1, v2, v3, v4, v5, v6);                   \
        _wr[(C0) + 1] = blur7(v1, v2, v3, v4, v5, v6, v7);                   \
        _wr[(C0) + 2] = blur7(v2, v3, v4, v5, v6, v7, v8);                   \
        _wr[(C0) + 3] = blur7(v3, v4, v5, v6, v7, v8, v9);                   \
    } while (0)

    // prologue: stage first slice into buffer 0
    STAGE(0, d0 - 3);

    int buf = 0;
    for (int k = 0; k < NS; ++k) {
        const int din = d0 - 3 + k;

        // raw[buf]'s gloads are the oldest outstanding vmem; the only newer
        // ops are this wave's 4 stores (once k>6). Count is exec-mask-proof.
        if (k <= 6) { asm volatile("s_waitcnt vmcnt(0)" ::: "memory"); }
        else        { asm volatile("s_waitcnt vmcnt(4)" ::: "memory"); }

        // issue next slice's async loads into the other buffer; they have
        // the whole W+H+store phase to land.
        if (k + 1 < NS) STAGE(buf ^ 1, din + 1);

        // W-blur (conflict-free stride-23 reads), intra-wave DS ordering
        WGRP(w1base, g1r, g1c);
        if (hasG2) WGRP(w2base, g2r, g2c);

        // H-blur: 10 wb reads -> 4 new ring values (rows 4q..4q+3)
        {
            float4 t0 = wb[4 * q + 0][lw];
            float4 t1 = wb[4 * q + 1][lw];
            float4 t2 = wb[4 * q + 2][lw];
            float4 t3 = wb[4 * q + 3][lw];
            float4 t4 = wb[4 * q + 4][lw];
            float4 t5 = wb[4 * q + 5][lw];
            float4 t6 = wb[4 * q + 6][lw];
            float4 t7 = wb[4 * q + 7][lw];
            float4 t8 = wb[4 * q + 8][lw];
            float4 t9 = wb[4 * q + 9][lw];
            float4 va = blur7(t0, t1, t2, t3, t4, t5, t6);
            float4 vb = blur7(t1, t2, t3, t4, t5, t6, t7);
            float4 vc = blur7(t2, t3, t4, t5, t6, t7, t8);
            float4 vd = blur7(t3, t4, t5, t6, t7, t8, t9);
            qa0=qa1; qa1=qa2; qa2=qa3; qa3=qa4; qa4=qa5; qa5=qa6; qa6=va;
            qb0=qb1; qb1=qb2; qb2=qb3; qb3=qb4; qb4=qb5; qb5=qb6; qb6=vb;
            qc0=qc1; qc1=qc2; qc2=qc3; qc3=qc4; qc4=qc5; qc5=qc6; qc6=vc;
            qd0=qd1; qd1=qd2; qd2=qd3; qd3=qd4; qd4=qd5; qd5=qd6; qd6=vd;
        }

        // emit 4 output rows for dout = din-3 once rings are primed
        if (k >= 6) {
            const int dout = din - 3;
            float4 oa = blur7(qa0, qa1, qa2, qa3, qa4, qa5, qa6);
            float4 ob = blur7(qb0, qb1, qb2, qb3, qb4, qb5, qb6);
            float4 oc = blur7(qc0, qc1, qc2, qc3, qc4, qc5, qc6);
            float4 od = blur7(qd0, qd1, qd2, qd3, qd4, qd5, qd6);
            const size_t base = nbase + (size_t)dout * SLICE + (size_t)(h0 + 4 * q) * DIM + (w0 + lw);
            out[base + 0 * DIM] = oa;
            out[base + 1 * DIM] = ob;
            out[base + 2 * DIM] = oc;
            out[base + 3 * DIM] = od;
        }
        buf ^= 1;
    }
#undef STAGE
#undef WGRP
}

extern "C" void kernel_launch(void* const* d_in, const int* in_sizes, int n_in,
                              void* d_out, int out_size, void* d_ws, size_t ws_size,
                              hipStream_t stream) {
    const float4* in = (const float4*)d_in[0];
    float4* out = (float4*)d_out;
    gauss3d_fused<<<NBLK, 64, 0, stream>>>(in, out);
}

// Round 22
// 73.127 us; speedup vs baseline: 1.4507x; 1.4507x over previous
//
#include <hip/hip_runtime.h>

// Separable 3D Gaussian blur (sigma=1, truncate=3 -> 7 taps), SAME zero padding.
// (N=2, D=160, H=160, W=160, C=4) float32 == float4 over C.
// Round 22 = R18/R19 wave-autonomous base + INTRA-WAVE software pipeline:
//   H-blur runs one slice BEHIND W-blur. wb is double-buffered as TWO
//   SEPARATE __shared__ arrays (wbA/wbB) so alias analysis is trivial and the
//   compiler can interleave H(k-1) ds_reads+VALU with W(k) ds ops -- removing
//   the W->H lgkmcnt serialization from every slice. No barriers (1-wave
//   blocks, in-order DS per wave). Loop unrolled x2 for static buffer roles.
//   R21 lesson: keep register prefetch (gload_lds's vmcnt drain kills at low
//   TLP); R13's failure was fp16-cvt+block-barriers, not pipelining per se.
// Kept from R19: 16x16 tile/wave, CHUNK=16, 2000 1-wave blocks = 8 XCDs x 250
// exact bijective swizzle, raw[22][23] f4 single-buffered, W-blur 88 groups
// (10 reads -> 4 outputs), H-blur 4 rows/lane + 4 D-rings, prefetch-1.
// LDS: raw 8.1 + wbA 6.0 + wbB 6.0 = 20.1 KB -> 7 blocks/CU (grid caps 7.8).
// Spill canary: WRITE_SIZE must stay ~130 MB.

#define THT 16
#define TWT 16
#define CHUNK 16
#define NS (CHUNK + 6)      // 22 slices per wave
#define DIM 160
#define SLICE (DIM * DIM)
#define HALON (22 * 22)     // 484 staged f4 per slice
#define NBLK 2000           // 2n x 10th x 10tw x 10chunk = 8 XCDs x 250

#define W0 0.004433048f
#define W1 0.054005582f
#define W2 0.242036229f
#define W3 0.399050300f

__device__ __forceinline__ float4 blur7(float4 a0, float4 a1, float4 a2, float4 a3,
                                        float4 a4, float4 a5, float4 a6) {
    float4 r;
    r.x = W0 * (a0.x + a6.x) + W1 * (a1.x + a5.x) + W2 * (a2.x + a4.x) + W3 * a3.x;
    r.y = W0 * (a0.y + a6.y) + W1 * (a1.y + a5.y) + W2 * (a2.y + a4.y) + W3 * a3.y;
    r.z = W0 * (a0.z + a6.z) + W1 * (a1.z + a5.z) + W2 * (a2.z + a4.z) + W3 * a3.z;
    r.w = W0 * (a0.w + a6.w) + W1 * (a1.w + a5.w) + W2 * (a2.w + a4.w) + W3 * a3.w;
    return r;
}

__global__ __launch_bounds__(64, 2)
void gauss3d_fused(const float4* __restrict__ in, float4* __restrict__ out) {
    // bijective XCD-chunked swizzle: 2000 = 8 * 250 exactly.
    const int bid = blockIdx.x;
    int wid = (bid & 7) * (NBLK / 8) + (bid >> 3);

    const int lane = threadIdx.x;   // 0..63

    const int tw    = wid % 10;  wid /= 10;
    const int th    = wid % 10;  wid /= 10;
    const int chunk = wid % 10;  wid /= 10;
    const int n     = wid;          // 0..1

    const int h0 = th * THT;
    const int w0 = tw * TWT;
    const int d0 = chunk * CHUNK;

    __shared__ float4 raw[22][23];   // halo tile, +1 col pad
    __shared__ float4 wbA[22][17];   // W-blurred, even slices
    __shared__ float4 wbB[22][17];   // W-blurred, odd slices

    const size_t nbase = (size_t)n * DIM * SLICE;
    const float4 z = make_float4(0.f, 0.f, 0.f, 0.f);

    // ---- stage constants: 484 halo f4 over 64 lanes (8 slots) ----
    int  soff[8], ridx[8];
    bool sok[8];
    #pragma unroll
    for (int s = 0; s < 8; ++s) {
        const int j = lane + 64 * s;
        const bool has = (j < HALON);
        const int rr = has ? (j / 22) : 0, cc = has ? (j % 22) : 0;
        const int gh = h0 + rr - 3, gw = w0 + cc - 3;
        const bool ok = has && gh >= 0 && gh < DIM && gw >= 0 && gw < DIM;
        soff[s] = ok ? (gh * DIM + gw) : 0;
        sok[s]  = ok;
        ridx[s] = rr * 23 + cc;
    }
    const bool has7 = (lane + 448 < HALON);   // lane < 36

    // ---- W-blur groups: 88 groups of 4 outputs ----
    const int g1r = lane >> 2, g1c = (lane & 3) * 4;
    const bool hasG2 = (lane < 24);
    const int g2r = (64 + lane) >> 2, g2c = ((64 + lane) & 3) * 4;

    // ---- H-blur: q = lane>>4 -> rows 4q..4q+3, lw = lane&15 ----
    const int q  = lane >> 4;
    const int lw = lane & 15;

    // 4 D-rings (output rows 4q..4q+3), 7 deep each
    float4 qa0=z,qa1=z,qa2=z,qa3=z,qa4=z,qa5=z,qa6=z;
    float4 qb0=z,qb1=z,qb2=z,qb3=z,qb4=z,qb5=z,qb6=z;
    float4 qc0=z,qc1=z,qc2=z,qc3=z,qc4=z,qc5=z,qc6=z;
    float4 qd0=z,qd1=z,qd2=z,qd3=z,qd4=z,qd5=z,qd6=z;

    float4 pf0, pf1, pf2, pf3, pf4, pf5, pf6, pf7;

#define PREFETCH(DSL)                                                        \
    do {                                                                     \
        const int _d = (DSL);                                                \
        const bool _inr = (_d >= 0) && (_d < DIM);                           \
        const float4* _s = in + nbase + (size_t)(_inr ? _d : 0) * SLICE;     \
        pf0 = (_inr && sok[0]) ? _s[soff[0]] : z;                            \
        pf1 = (_inr && sok[1]) ? _s[soff[1]] : z;                            \
        pf2 = (_inr && sok[2]) ? _s[soff[2]] : z;                            \
        pf3 = (_inr && sok[3]) ? _s[soff[3]] : z;                            \
        pf4 = (_inr && sok[4]) ? _s[soff[4]] : z;                            \
        pf5 = (_inr && sok[5]) ? _s[soff[5]] : z;                            \
        pf6 = (_inr && sok[6]) ? _s[soff[6]] : z;                            \
        pf7 = (_inr && sok[7]) ? _s[soff[7]] : z;                            \
    } while (0)

#define COMMIT()                                                             \
    do {                                                                     \
        float4* rb = &raw[0][0];                                             \
        rb[ridx[0]] = pf0;                                                   \
        rb[ridx[1]] = pf1;                                                   \
        rb[ridx[2]] = pf2;                                                   \
        rb[ridx[3]] = pf3;                                                   \
        rb[ridx[4]] = pf4;                                                   \
        rb[ridx[5]] = pf5;                                                   \
        rb[ridx[6]] = pf6;                                                   \
        if (has7) rb[ridx[7]] = pf7;                                         \
    } while (0)

#define WGRP(WBC, R, C0)                                                     \
    do {                                                                     \
        const float4* _rr = &raw[R][0];                                      \
        float4 v0 = _rr[(C0) + 0];                                           \
        float4 v1 = _rr[(C0) + 1];                                           \
        float4 v2 = _rr[(C0) + 2];                                           \
        float4 v3 = _rr[(C0) + 3];                                           \
        float4 v4 = _rr[(C0) + 4];                                           \
        float4 v5 = _rr[(C0) + 5];                                           \
        float4 v6 = _rr[(C0) + 6];                                           \
        float4 v7 = _rr[(C0) + 7];                                           \
        float4 v8 = _rr[(C0) + 8];                                           \
        float4 v9 = _rr[(C0) + 9];                                           \
        float4* _wr = &WBC[R][0];                                            \
        _wr[(C0) + 0] = blur7(v0, v1, v2, v3, v4, v5, v6);                   \
        _wr[(C0) + 1] = blur7(v1, v2, v3, v4, v5, v6, v7);                   \
        _wr[(C0) + 2] = blur7(v2, v3, v4, v5, v6, v7, v8);                   \
        _wr[(C0) + 3] = blur7(v3, v4, v5, v6, v7, v8, v9);                   \
    } while (0)

// H-blur for slice kH from buffer WBP; guards are wave-uniform.
#define HPH(WBP, KH)                                                         \
    do {                                                                     \
        const int _kh = (KH);                                                \
        if (_kh >= 0) {                                                      \
            float4 t0 = WBP[4 * q + 0][lw];                                  \
            float4 t1 = WBP[4 * q + 1][lw];                                  \
            float4 t2 = WBP[4 * q + 2][lw];                                  \
            float4 t3 = WBP[4 * q + 3][lw];                                  \
            float4 t4 = WBP[4 * q + 4][lw];                                  \
            float4 t5 = WBP[4 * q + 5][lw];                                  \
            float4 t6 = WBP[4 * q + 6][lw];                                  \
            float4 t7 = WBP[4 * q + 7][lw];                                  \
            float4 t8 = WBP[4 * q + 8][lw];                                  \
            float4 t9 = WBP[4 * q + 9][lw];                                  \
            float4 va = blur7(t0, t1, t2, t3, t4, t5, t6);                   \
            float4 vb = blur7(t1, t2, t3, t4, t5, t6, t7);                   \
            float4 vc = blur7(t2, t3, t4, t5, t6, t7, t8);                   \
            float4 vd = blur7(t3, t4, t5, t6, t7, t8, t9);                   \
            qa0=qa1; qa1=qa2; qa2=qa3; qa3=qa4; qa4=qa5; qa5=qa6; qa6=va;    \
            qb0=qb1; qb1=qb2; qb2=qb3; qb3=qb4; qb4=qb5; qb5=qb6; qb6=vb;    \
            qc0=qc1; qc1=qc2; qc2=qc3; qc3=qc4; qc4=qc5; qc5=qc6; qc6=vc;    \
            qd0=qd1; qd1=qd2; qd2=qd3; qd3=qd4; qd4=qd5; qd5=qd6; qd6=vd;    \
            if (_kh >= 6) {                                                  \
                const int dout = d0 + _kh - 6;                               \
                float4 oa = blur7(qa0, qa1, qa2, qa3, qa4, qa5, qa6);        \
                float4 ob = blur7(qb0, qb1, qb2, qb3, qb4, qb5, qb6);        \
                float4 oc = blur7(qc0, qc1, qc2, qc3, qc4, qc5, qc6);        \
                float4 od = blur7(qd0, qd1, qd2, qd3, qd4, qd5, qd6);        \
                const size_t base = nbase + (size_t)dout * SLICE             \
                                  + (size_t)(h0 + 4 * q) * DIM + (w0 + lw);  \
                out[base + 0 * DIM] = oa;                                    \
                out[base + 1 * DIM] = ob;                                    \
                out[base + 2 * DIM] = oc;                                    \
                out[base + 3 * DIM] = od;                                    \
            }                                                                \
        }                                                                    \
    } while (0)

    PREFETCH(d0 - 3);

    // main loop: pairs (even k -> wbA, odd k -> wbB); H runs one slice behind.
    for (int k2 = 0; k2 < NS; k2 += 2) {
        // even slice k = k2: W -> wbA; H consumes wbB (slice k2-1)
        {
            COMMIT();
            if (k2 + 1 < NS) PREFETCH(d0 - 3 + k2 + 1);
            WGRP(wbA, g1r, g1c);
            if (hasG2) WGRP(wbA, g2r, g2c);
            HPH(wbB, k2 - 1);
        }
        // odd slice k = k2+1: W -> wbB; H consumes wbA (slice k2)
        {
            COMMIT();
            if (k2 + 2 < NS) PREFETCH(d0 - 3 + k2 + 2);
            WGRP(wbB, g1r, g1c);
            if (hasG2) WGRP(wbB, g2r, g2c);
            HPH(wbA, k2);
        }
    }
    // epilogue: H for the last slice (NS-1 = 21, odd -> wbB)
    HPH(wbB, NS - 1);

#undef PREFETCH
#undef COMMIT
#undef WGRP
#undef HPH
}

extern "C" void kernel_launch(void* const* d_in, const int* in_sizes, int n_in,
                              void* d_out, int out_size, void* d_ws, size_t ws_size,
                              hipStream_t stream) {
    const float4* in = (const float4*)d_in[0];
    float4* out = (float4*)d_out;
    gauss3d_fused<<<NBLK, 64, 0, stream>>>(in, out);
}